// Round 10
// baseline (698.473 us; speedup 1.0000x reference)
//
#include <hip/hip_runtime.h>

#define NPTS 16384
#define MAGIC 0x51C0FFEE7EA5E55AULL  // 64-bit validity token (can't collide with 0xAA poison)

typedef short bf16x8 __attribute__((ext_vector_type(8)));
typedef float f32x16 __attribute__((ext_vector_type(16)));
typedef unsigned short us8v __attribute__((ext_vector_type(8)));

__device__ __forceinline__ unsigned short f2bf(float x) {
  unsigned int u = __float_as_uint(x);
  u = (u + 0x7FFFu + ((u >> 16) & 1u)) >> 16;   // RNE
  return (unsigned short)u;
}
__device__ __forceinline__ float bf2f(unsigned short h) {
  return __uint_as_float(((unsigned int)h) << 16);
}

// agent-scope fences (one-time cost; NOT per poll iteration)
__device__ __forceinline__ void fence_release_agent() {
  __builtin_amdgcn_fence(__ATOMIC_RELEASE, "agent");
}
__device__ __forceinline__ void fence_acquire_agent() {
  __builtin_amdgcn_fence(__ATOMIC_ACQUIRE, "agent");
}

// F features (verified rounds 3-8): h0={xh,xh,xl,xl,yh,yh,yl,yl} of -2p;
// h1={zh,zh,zl,zl,whi,wmid,wlo,0}, w=|p|^2 split 3-way.  With G-frag
// {xh,xl,xh,xl,yh,yl,yh,yl | zh,zl,zh,zl,1,1,1,0}: F.G = |p|^2 - 2 p.q.
__device__ __forceinline__ void buildF(float x, float y, float z,
                                       us8v& h0, us8v& h1) {
  float t;
  t = -2.0f * x; const unsigned short xh = f2bf(t), xl = f2bf(t - bf2f(xh));
  t = -2.0f * y; const unsigned short yh = f2bf(t), yl = f2bf(t - bf2f(yh));
  t = -2.0f * z; const unsigned short zh = f2bf(t), zl = f2bf(t - bf2f(zh));
  const float w = x * x + y * y + z * z;
  const unsigned short wh = f2bf(w);
  const float w1 = w - bf2f(wh);
  const unsigned short wm = f2bf(w1);
  const unsigned short wl = f2bf(w1 - bf2f(wm));
  h0[0] = xh; h0[1] = xh; h0[2] = xl; h0[3] = xl;
  h0[4] = yh; h0[5] = yh; h0[6] = yl; h0[7] = yl;
  h1[0] = zh; h1[1] = zh; h1[2] = zl; h1[3] = zl;
  h1[4] = wh; h1[5] = wm; h1[6] = wl; h1[7] = 0;
}

// Poll a token WITHOUT per-iteration cache invalidates: relaxed agent-scope
// load (reads the coherence point, no buffer_inv).  Caller issues ONE
// acquire fence after success.  Round-8 lesson: acquire-per-poll invalidated
// the per-XCD L2 every iteration -> 772 MB FETCH / 1.5 GB WRITE of thrash.
__device__ __forceinline__ void poll_token(const unsigned long long* p) {
  while (__hip_atomic_load(p, __ATOMIC_RELAXED, __HIP_MEMORY_SCOPE_AGENT) != MAGIC)
    __builtin_amdgcn_s_sleep(2);
}

// ---------------------------------------------------------------------------
// Single-dispatch kernel.  grid = 512 = dir(2) x ag(16) x cc(16), 512 thr
// (8 waves), 32 KB LDS, 2 blocks/CU.  Worker: build F for B-chunk (1024 pts)
// in LDS, 8 waves x 4 A-tiles, 32-tile unrolled MFMA+min3 loop, write f32
// partial[dir][cc][q].  RELEASE fence + relaxed token.  Combiner (cc==0):
// relaxed-poll 16 tokens, ONE acquire fence, min-fold + fixed-tree sum ->
// gsum[dir*16+ag] + gtoken.  Block 0: relaxed-poll 32 gtokens, one fence,
// fixed-order sum -> out.  DAG waits => deadlock-free at any residency;
// magic tokens => poison/garbage safe; partials bit-identical across replays
// => stale-token fast path safe.
// ---------------------------------------------------------------------------
__global__ __launch_bounds__(512, 4) void chamfer_mono_kernel(
    const float* __restrict__ adv, const float* __restrict__ ori,
    float* __restrict__ partial /* [2][16][16384] */,
    float* __restrict__ gsum /* [32] */,
    unsigned long long* __restrict__ tokens /* [512] */,
    unsigned long long* __restrict__ gtokens /* [32] */,
    float* __restrict__ out) {
  __shared__ short lds[16384];   // 32 KB F buffer
  __shared__ float redbuf[8];

  const int bid = blockIdx.x;
  const int dir = bid >> 8;
  const int rr  = bid & 255;
  const int ag  = rr >> 4;   // 0..15 A-group (1024 pts)
  const int cc  = rr & 15;   // 0..15 B-chunk (1024 pts)

  const float* __restrict__ A = dir ? ori : adv;
  const float* __restrict__ B = dir ? adv : ori;

  const int tid  = threadIdx.x;  // 0..511
  const int w    = tid >> 6;
  const int lane = tid & 63;
  const int col  = lane & 31;
  const int half = lane >> 5;

  // ---- build F into LDS: thread t handles local points t and t+512 ----
  // layout: point p -> byte (p>>5)*1024 + (p&31)*16 (+512 for half 1)
#pragma unroll
  for (int pp = 0; pp < 2; ++pp) {
    const int p = tid + pp * 512;
    const float* bp = B + (size_t)(cc * 1024 + p) * 3;
    us8v h0, h1;
    buildF(bp[0], bp[1], bp[2], h0, h1);
    char* base = (char*)lds + (p >> 5) * 1024 + (p & 31) * 16;
    *(us8v*)base = h0;
    *(us8v*)(base + 512) = h1;
  }

  // ---- G fragments for this wave's 4 A-tiles ----
  const unsigned short ONE = 0x3F80;
  bf16x8 g[4];
  float q2[4];
  int q[4];
#pragma unroll
  for (int i = 0; i < 4; ++i) {
    const int qi = ag * 1024 + w * 128 + i * 32 + col;
    q[i] = qi;
    const float x = A[qi * 3], y = A[qi * 3 + 1], z = A[qi * 3 + 2];
    q2[i] = x * x + y * y + z * z;
    const unsigned short xh = f2bf(x), xl = f2bf(x - bf2f(xh));
    const unsigned short yh = f2bf(y), yl = f2bf(y - bf2f(yh));
    const unsigned short zh = f2bf(z), zl = f2bf(z - bf2f(zh));
    g[i][0] = half ? zh : xh; g[i][1] = half ? zl : xl;
    g[i][2] = half ? zh : xh; g[i][3] = half ? zl : xl;
    g[i][4] = half ? ONE : yh; g[i][5] = half ? ONE : yl;
    g[i][6] = half ? ONE : yh; g[i][7] = half ? (unsigned short)0 : yl;
  }

  __syncthreads();

  // ---- main loop: 32 tiles x (1 ds_read_b128 + 4 MFMA + 32 min3) ----
  const f32x16 zacc = {};
  float m[4] = {1e30f, 1e30f, 1e30f, 1e30f};
  const char* Lb = (const char*)lds + lane * 16;  // = col*16 + half*512

#pragma unroll
  for (int t = 0; t < 32; ++t) {
    const bf16x8 f = *(const bf16x8*)(Lb + t * 1024);
#pragma unroll
    for (int i = 0; i < 4; ++i) {
      const f32x16 a = __builtin_amdgcn_mfma_f32_32x32x16_bf16(f, g[i], zacc, 0, 0, 0);
      const float u0 = fminf(fminf(a[0], a[1]), a[2]);
      const float u1 = fminf(fminf(a[3], a[4]), a[5]);
      const float u2 = fminf(fminf(a[6], a[7]), a[8]);
      const float u3 = fminf(fminf(a[9], a[10]), a[11]);
      const float u4 = fminf(fminf(a[12], a[13]), a[14]);
      const float v0 = fminf(fminf(u0, u1), u2);
      const float v1 = fminf(fminf(u3, u4), a[15]);
      m[i] = fminf(fminf(m[i], v0), v1);
    }
  }

  // ---- epilogue: fold halves, add |q|^2, write f32 partial ----
  float* pslice = partial + (size_t)(dir * 16 + cc) * NPTS;
#pragma unroll
  for (int i = 0; i < 4; ++i) {
    const float mc = fminf(m[i], __shfl_xor(m[i], 32));
    const float d = fmaxf(mc + q2[i], 0.0f);
    if (half == 0) pslice[q[i]] = d;
  }

  __syncthreads();
  if (tid == 0) {
    fence_release_agent();
    __hip_atomic_store(&tokens[bid], MAGIC, __ATOMIC_RELAXED,
                       __HIP_MEMORY_SCOPE_AGENT);
  }

  // ---- combiner: cc==0 block of each (dir,ag) group ----
  if (cc == 0) {
    if (tid < 16) poll_token(&tokens[bid + tid]);
    __syncthreads();
    if (tid == 0) fence_acquire_agent();
    __syncthreads();  // fence (one L2 invalidate) done before any partial read

    const float* pb = partial + (size_t)(dir * 16) * NPTS + ag * 1024;
    float s = 0.0f;
#pragma unroll
    for (int pp = 0; pp < 2; ++pp) {
      const int j = tid + pp * 512;
      float mn = pb[j];
#pragma unroll
      for (int c = 1; c < 16; ++c) mn = fminf(mn, pb[(size_t)c * NPTS + j]);
      s += mn;
    }
    // fixed-topology block sum: wave butterfly + 8-entry LDS fold
#pragma unroll
    for (int off = 32; off > 0; off >>= 1) s += __shfl_xor(s, off);
    if (lane == 0) redbuf[w] = s;
    __syncthreads();
    if (tid == 0) {
      float gs = 0.0f;
#pragma unroll
      for (int i = 0; i < 8; ++i) gs += redbuf[i];
      const int gidx = dir * 16 + ag;
      gsum[gidx] = gs;
      fence_release_agent();
      __hip_atomic_store(&gtokens[gidx], MAGIC, __ATOMIC_RELAXED,
                         __HIP_MEMORY_SCOPE_AGENT);
    }
  }

  // ---- final: block 0, thread 0 ----
  if (bid == 0 && tid == 0) {
    for (int i = 0; i < 32; ++i) poll_token(&gtokens[i]);
    fence_acquire_agent();
    float tot = 0.0f;
    for (int i = 0; i < 32; ++i) tot += gsum[i];
    out[0] = tot * (1.0f / (float)NPTS);  // LOSS_WEIGHT = 1
  }
}

// ---------------------------------------------------------------------------
// Fallback (ws too small): round-2 VALU kernel + memset + reduce.
// ---------------------------------------------------------------------------
__global__ __launch_bounds__(256) void chamfer_valu_kernel(
    const float* __restrict__ adv, const float* __restrict__ ori,
    unsigned int* __restrict__ minbuf) {
  __shared__ float4 bt[512];
  const int bx = blockIdx.x;
  const int c = bx & 31;
  const int t = bx >> 5;
  const int dir = t & 1;
  const int ab = t >> 1;
  const float* __restrict__ A = dir ? ori : adv;
  const float* __restrict__ B = dir ? adv : ori;
  const int tid = threadIdx.x;
  for (int j = tid; j < 512; j += 256) {
    const float* bp = B + (size_t)(c * 512 + j) * 3;
    const float x = bp[0], y = bp[1], z = bp[2];
    bt[j] = make_float4(x, y, z, 0.5f * (x * x + y * y + z * z));
  }
  float nax[8], nay[8], naz[8], a2[8], mn[8];
#pragma unroll
  for (int k = 0; k < 8; ++k) {
    const int idx = ab * 2048 + k * 256 + tid;
    const float* ap = A + (size_t)idx * 3;
    const float x = ap[0], y = ap[1], z = ap[2];
    nax[k] = -x; nay[k] = -y; naz[k] = -z;
    a2[k] = x * x + y * y + z * z;
    mn[k] = 1e30f;
  }
  __syncthreads();
#pragma unroll 4
  for (int j = 0; j < 512; j += 2) {
    const float4 b0 = bt[j];
    const float4 b1 = bt[j + 1];
#pragma unroll
    for (int k = 0; k < 8; ++k) {
      const float t0 = fmaf(nax[k], b0.x, fmaf(nay[k], b0.y, fmaf(naz[k], b0.z, b0.w)));
      const float t1 = fmaf(nax[k], b1.x, fmaf(nay[k], b1.y, fmaf(naz[k], b1.z, b1.w)));
      mn[k] = fminf(fminf(mn[k], t0), t1);
    }
  }
#pragma unroll
  for (int k = 0; k < 8; ++k) {
    const int idx = ab * 2048 + k * 256 + tid;
    const float v = fmaf(2.0f, mn[k], a2[k]);
    atomicMin(&minbuf[dir * NPTS + idx], __float_as_uint(v));
  }
}

__global__ __launch_bounds__(1024) void chamfer_reduce_u32_kernel(
    const unsigned int* __restrict__ minbuf, float* __restrict__ out) {
  __shared__ float red[1024];
  const int tid = threadIdx.x;
  float s = 0.0f;
  for (int j = tid; j < 2 * NPTS; j += 1024) s += __uint_as_float(minbuf[j]);
  red[tid] = s;
  __syncthreads();
  for (int off = 512; off > 0; off >>= 1) {
    if (tid < off) red[tid] += red[tid + off];
    __syncthreads();
  }
  if (tid == 0) out[0] = red[0] * (1.0f / (float)NPTS);
}

extern "C" void kernel_launch(void* const* d_in, const int* in_sizes, int n_in,
                              void* d_out, int out_size, void* d_ws, size_t ws_size,
                              hipStream_t stream) {
  const float* adv = (const float*)d_in[0];
  const float* ori = (const float*)d_in[1];
  float* out = (float*)d_out;

  // ws layout: partial 2*16*16384*4 = 2 MB | gsum 128B | tokens 4 KB | gtokens 256B
  const size_t partial_bytes = (size_t)2 * 16 * NPTS * sizeof(float);
  const size_t gsum_off    = partial_bytes;
  const size_t tokens_off  = partial_bytes + 128;
  const size_t gtokens_off = tokens_off + 512 * sizeof(unsigned long long);
  const size_t need        = gtokens_off + 32 * sizeof(unsigned long long);

  if (ws_size >= need) {
    float* partial = (float*)d_ws;
    float* gsum = (float*)((char*)d_ws + gsum_off);
    unsigned long long* tokens = (unsigned long long*)((char*)d_ws + tokens_off);
    unsigned long long* gtokens = (unsigned long long*)((char*)d_ws + gtokens_off);
    chamfer_mono_kernel<<<512, 512, 0, stream>>>(adv, ori, partial, gsum,
                                                 tokens, gtokens, out);
  } else {
    unsigned int* minbuf = (unsigned int*)d_ws;
    (void)hipMemsetAsync(minbuf, 0x7F, (size_t)(2 * NPTS) * sizeof(unsigned int), stream);
    chamfer_valu_kernel<<<1024, 256, 0, stream>>>(adv, ori, minbuf);
    chamfer_reduce_u32_kernel<<<1, 1024, 0, stream>>>(minbuf, out);
  }
}

// Round 11
// 688.561 us; speedup vs baseline: 1.0144x; 1.0144x over previous
//
#include <hip/hip_runtime.h>

#define NPTS 16384

typedef short bf16x8 __attribute__((ext_vector_type(8)));
typedef float f32x16 __attribute__((ext_vector_type(16)));
typedef unsigned short us8v __attribute__((ext_vector_type(8)));

__device__ __forceinline__ unsigned short f2bf(float x) {
  unsigned int u = __float_as_uint(x);
  u = (u + 0x7FFFu + ((u >> 16) & 1u)) >> 16;   // RNE
  return (unsigned short)u;
}
__device__ __forceinline__ float bf2f(unsigned short h) {
  return __uint_as_float(((unsigned int)h) << 16);
}

// ---------------------------------------------------------------------------
// Prepack (verified rounds 3/4/7): per point p, A-operand features F_p[16]
// bf16: per coord c: {hi(-2p_c), hi, lo, lo}; ch12-14 = 3-way split of |p|^2;
// ch15 = 0.  S[p][q] = F_p . G_q = |p|^2 - 2 p.q; d = S + |q|^2.
// Tile-interleaved layout = exact 32x32x16 A-frag order (tile t at byte
// t*1024; point j=p&31, half h at j*16 + h*512), so global_load_lds staging
// and ds_read_b128 are linear.  Also initializes minbuf.
// ---------------------------------------------------------------------------
__global__ __launch_bounds__(256) void prepack_kernel(
    const float* __restrict__ adv, const float* __restrict__ ori,
    unsigned short* __restrict__ Fall, unsigned int* __restrict__ minbuf) {
  const int id = blockIdx.x * 256 + threadIdx.x;  // 0..32767
  minbuf[id] = 0x7F7F7F7Fu;  // > any finite non-negative float bit pattern

  const int s = id >> 14;
  const int p = id & (NPTS - 1);
  const float* P = s ? ori : adv;
  const float x = P[p * 3 + 0], y = P[p * 3 + 1], z = P[p * 3 + 2];

  unsigned short o[16];
  const float co[3] = {x, y, z};
#pragma unroll
  for (int c = 0; c < 3; ++c) {
    const float t = -2.0f * co[c];
    const unsigned short hi = f2bf(t);
    const unsigned short lo = f2bf(t - bf2f(hi));
    o[4 * c + 0] = hi; o[4 * c + 1] = hi;
    o[4 * c + 2] = lo; o[4 * c + 3] = lo;
  }
  const float w = x * x + y * y + z * z;
  const unsigned short whi = f2bf(w);
  const float w1 = w - bf2f(whi);
  const unsigned short wmid = f2bf(w1);
  const unsigned short wlo = f2bf(w1 - bf2f(wmid));
  o[12] = whi; o[13] = wmid; o[14] = wlo; o[15] = 0;

  unsigned short* base = Fall + (size_t)s * (NPTS * 16) + (p >> 5) * 512 + (p & 31) * 8;
  us8v h0, h1;
#pragma unroll
  for (int i = 0; i < 8; ++i) { h0[i] = o[i]; h1[i] = o[8 + i]; }
  *(us8v*)(base) = h0;          // half 0 (ch 0-7)
  *(us8v*)(base + 256) = h1;    // half 1 (ch 8-15)
}

// ---------------------------------------------------------------------------
// Main: grid 512 = dir(2) x ag(16) x cc(16), 512 thr (8 waves), 32 KB LDS,
// 2 blocks/CU (4 waves/SIMD).  ONE B-stage of 1024 pts (32 KB) via
// global_load_lds; each wave owns 4 A-tiles (128 A-points) -> 1 ds_read_b128
// feeds 4 MFMAs (LDS traffic halved vs r4: 512 KB/CU ~ 2.5 us < VALU 3.4 us).
// Fold = depth-3 min3 tree (8 min3/MFMA).  Combine via deterministic
// atomicMin on uint bit patterns.
// ---------------------------------------------------------------------------
__global__ __launch_bounds__(512, 4) void chamfer_mfma_kernel(
    const float* __restrict__ adv, const float* __restrict__ ori,
    const unsigned short* __restrict__ Fall,
    unsigned int* __restrict__ minbuf) {
  __shared__ short lds[16384];  // 32 KB

  const int bid = blockIdx.x;
  const int dir = bid >> 8;
  const int rr  = bid & 255;
  const int ag  = rr >> 4;   // 0..15 A-group (1024 pts)
  const int cc  = rr & 15;   // 0..15 B-chunk (1024 pts = 32 tiles)

  const float* __restrict__ A = dir ? ori : adv;
  const unsigned short* __restrict__ F = Fall + (size_t)(1 - dir) * (NPTS * 16);

  const int tid  = threadIdx.x;
  const int w    = tid >> 6;
  const int lane = tid & 63;
  const int col  = lane & 31;
  const int half = lane >> 5;

  // ---- stage B-chunk F (32 KB) via global_load_lds: 8 waves x 4 x 1KB ----
  const char* src = (const char*)(F + (size_t)cc * 16384);
#pragma unroll
  for (int s = 0; s < 4; ++s) {
    const int seg = w * 4 + s;
    __builtin_amdgcn_global_load_lds(
        (const __attribute__((address_space(1))) void*)(src + seg * 1024 + lane * 16),
        (__attribute__((address_space(3))) void*)((char*)lds + seg * 1024),
        16, 0, 0);
  }

  // ---- G fragments for this wave's 4 A-tiles ----
  const unsigned short ONE = 0x3F80;
  bf16x8 g[4];
  float q2[4];
  int q[4];
#pragma unroll
  for (int i = 0; i < 4; ++i) {
    const int qi = ag * 1024 + w * 128 + i * 32 + col;
    q[i] = qi;
    const float x = A[qi * 3], y = A[qi * 3 + 1], z = A[qi * 3 + 2];
    q2[i] = x * x + y * y + z * z;
    const unsigned short xh = f2bf(x), xl = f2bf(x - bf2f(xh));
    const unsigned short yh = f2bf(y), yl = f2bf(y - bf2f(yh));
    const unsigned short zh = f2bf(z), zl = f2bf(z - bf2f(zh));
    g[i][0] = half ? zh : xh; g[i][1] = half ? zl : xl;
    g[i][2] = half ? zh : xh; g[i][3] = half ? zl : xl;
    g[i][4] = half ? ONE : yh; g[i][5] = half ? ONE : yl;
    g[i][6] = half ? ONE : yh; g[i][7] = half ? (unsigned short)0 : yl;
  }

  __syncthreads();  // compiler emits vmcnt(0) drain before barrier -> stage done

  // ---- main loop: 32 tiles x (1 ds_read_b128 + 4 MFMA + 32 min3) ----
  const f32x16 zacc = {};
  float m[4] = {1e30f, 1e30f, 1e30f, 1e30f};
  const char* Lb = (const char*)lds + lane * 16;  // = col*16 + half*512

#pragma unroll
  for (int t = 0; t < 32; ++t) {
    const bf16x8 f = *(const bf16x8*)(Lb + t * 1024);  // imm-offset ds_read_b128
#pragma unroll
    for (int i = 0; i < 4; ++i) {
      const f32x16 a = __builtin_amdgcn_mfma_f32_32x32x16_bf16(f, g[i], zacc, 0, 0, 0);
      const float u0 = fminf(fminf(a[0], a[1]), a[2]);
      const float u1 = fminf(fminf(a[3], a[4]), a[5]);
      const float u2 = fminf(fminf(a[6], a[7]), a[8]);
      const float u3 = fminf(fminf(a[9], a[10]), a[11]);
      const float u4 = fminf(fminf(a[12], a[13]), a[14]);
      const float v0 = fminf(fminf(u0, u1), u2);
      const float v1 = fminf(fminf(u3, u4), a[15]);
      m[i] = fminf(fminf(m[i], v0), v1);
    }
  }

  // ---- epilogue: fold halves, add |q|^2, atomicMin combine ----
#pragma unroll
  for (int i = 0; i < 4; ++i) {
    const float mc = fminf(m[i], __shfl_xor(m[i], 32));
    const float d = fmaxf(mc + q2[i], 0.0f);
    if (half == 0)
      atomicMin(&minbuf[dir * NPTS + q[i]], __float_as_uint(d));
  }
}

// Single block: sum all 2*NPTS per-point mins (uint4-vectorized), /NPTS.
__global__ __launch_bounds__(1024) void chamfer_reduce_kernel(
    const unsigned int* __restrict__ minbuf, float* __restrict__ out) {
  __shared__ float red[1024];
  const int tid = threadIdx.x;
  const uint4* mb4 = (const uint4*)minbuf;
  float s = 0.0f;
#pragma unroll
  for (int it = 0; it < 8; ++it) {
    const uint4 v = mb4[it * 1024 + tid];
    s += __uint_as_float(v.x) + __uint_as_float(v.y) +
         __uint_as_float(v.z) + __uint_as_float(v.w);
  }
  red[tid] = s;
  __syncthreads();
  for (int off = 512; off > 0; off >>= 1) {
    if (tid < off) red[tid] += red[tid + off];
    __syncthreads();
  }
  if (tid == 0) out[0] = red[0] * (1.0f / (float)NPTS);  // LOSS_WEIGHT = 1
}

// ---------------------------------------------------------------------------
// Fallback (ws too small): round-2 VALU kernel + memset + reduce.
// ---------------------------------------------------------------------------
__global__ __launch_bounds__(256) void chamfer_valu_kernel(
    const float* __restrict__ adv, const float* __restrict__ ori,
    unsigned int* __restrict__ minbuf) {
  __shared__ float4 bt[512];
  const int bx = blockIdx.x;
  const int c = bx & 31;
  const int t = bx >> 5;
  const int dir = t & 1;
  const int ab = t >> 1;
  const float* __restrict__ A = dir ? ori : adv;
  const float* __restrict__ B = dir ? adv : ori;
  const int tid = threadIdx.x;
  for (int j = tid; j < 512; j += 256) {
    const float* bp = B + (size_t)(c * 512 + j) * 3;
    const float x = bp[0], y = bp[1], z = bp[2];
    bt[j] = make_float4(x, y, z, 0.5f * (x * x + y * y + z * z));
  }
  float nax[8], nay[8], naz[8], a2[8], mn[8];
#pragma unroll
  for (int k = 0; k < 8; ++k) {
    const int idx = ab * 2048 + k * 256 + tid;
    const float* ap = A + (size_t)idx * 3;
    const float x = ap[0], y = ap[1], z = ap[2];
    nax[k] = -x; nay[k] = -y; naz[k] = -z;
    a2[k] = x * x + y * y + z * z;
    mn[k] = 1e30f;
  }
  __syncthreads();
#pragma unroll 4
  for (int j = 0; j < 512; j += 2) {
    const float4 b0 = bt[j];
    const float4 b1 = bt[j + 1];
#pragma unroll
    for (int k = 0; k < 8; ++k) {
      const float t0 = fmaf(nax[k], b0.x, fmaf(nay[k], b0.y, fmaf(naz[k], b0.z, b0.w)));
      const float t1 = fmaf(nax[k], b1.x, fmaf(nay[k], b1.y, fmaf(naz[k], b1.z, b1.w)));
      mn[k] = fminf(fminf(mn[k], t0), t1);
    }
  }
#pragma unroll
  for (int k = 0; k < 8; ++k) {
    const int idx = ab * 2048 + k * 256 + tid;
    const float v = fmaf(2.0f, mn[k], a2[k]);
    atomicMin(&minbuf[dir * NPTS + idx], __float_as_uint(v));
  }
}

extern "C" void kernel_launch(void* const* d_in, const int* in_sizes, int n_in,
                              void* d_out, int out_size, void* d_ws, size_t ws_size,
                              hipStream_t stream) {
  const float* adv = (const float*)d_in[0];
  const float* ori = (const float*)d_in[1];
  float* out = (float*)d_out;
  unsigned int* minbuf = (unsigned int*)d_ws;

  const size_t need = 131072 + (size_t)2 * NPTS * 16 * sizeof(unsigned short);  // 128K + 1M

  if (ws_size >= need) {
    unsigned short* Fall = (unsigned short*)((char*)d_ws + 131072);
    prepack_kernel<<<128, 256, 0, stream>>>(adv, ori, Fall, minbuf);  // also inits minbuf
    chamfer_mfma_kernel<<<512, 512, 0, stream>>>(adv, ori, Fall, minbuf);
  } else {
    (void)hipMemsetAsync(minbuf, 0x7F, (size_t)(2 * NPTS) * sizeof(unsigned int), stream);
    chamfer_valu_kernel<<<1024, 256, 0, stream>>>(adv, ori, minbuf);
  }
  chamfer_reduce_kernel<<<1, 1024, 0, stream>>>(minbuf, out);
}

// Round 12
// 339.895 us; speedup vs baseline: 2.0550x; 2.0258x over previous
//
#include <hip/hip_runtime.h>

#define NPTS 16384

typedef short bf16x8 __attribute__((ext_vector_type(8)));
typedef float f32x16 __attribute__((ext_vector_type(16)));
typedef unsigned short us8v __attribute__((ext_vector_type(8)));

__device__ __forceinline__ unsigned short f2bf(float x) {
  unsigned int u = __float_as_uint(x);
  u = (u + 0x7FFFu + ((u >> 16) & 1u)) >> 16;   // RNE
  return (unsigned short)u;
}
__device__ __forceinline__ float bf2f(unsigned short h) {
  return __uint_as_float(((unsigned int)h) << 16);
}

// ---------------------------------------------------------------------------
// Prepack (verified r3/r4/r7): per point p, A-operand features F_p[16] bf16:
// per coord c: {hi(-2p_c), hi, lo, lo}; ch12-14 = 3-way split of |p|^2;
// ch15 = 0.  S[p][q] = F_p . G_q = |p|^2 - 2 p.q; d = S + |q|^2.
// Tile-interleaved = exact 32x32x16 A-frag order -> staging and ds_read_b128
// linear.  Also initializes minbuf.
// ---------------------------------------------------------------------------
__global__ __launch_bounds__(256) void prepack_kernel(
    const float* __restrict__ adv, const float* __restrict__ ori,
    unsigned short* __restrict__ Fall, unsigned int* __restrict__ minbuf) {
  const int id = blockIdx.x * 256 + threadIdx.x;  // 0..32767
  minbuf[id] = 0x7F7F7F7Fu;  // > any finite non-negative float bit pattern

  const int s = id >> 14;
  const int p = id & (NPTS - 1);
  const float* P = s ? ori : adv;
  const float x = P[p * 3 + 0], y = P[p * 3 + 1], z = P[p * 3 + 2];

  unsigned short o[16];
  const float co[3] = {x, y, z};
#pragma unroll
  for (int c = 0; c < 3; ++c) {
    const float t = -2.0f * co[c];
    const unsigned short hi = f2bf(t);
    const unsigned short lo = f2bf(t - bf2f(hi));
    o[4 * c + 0] = hi; o[4 * c + 1] = hi;
    o[4 * c + 2] = lo; o[4 * c + 3] = lo;
  }
  const float w = x * x + y * y + z * z;
  const unsigned short whi = f2bf(w);
  const float w1 = w - bf2f(whi);
  const unsigned short wmid = f2bf(w1);
  const unsigned short wlo = f2bf(w1 - bf2f(wmid));
  o[12] = whi; o[13] = wmid; o[14] = wlo; o[15] = 0;

  unsigned short* base = Fall + (size_t)s * (NPTS * 16) + (p >> 5) * 512 + (p & 31) * 8;
  us8v h0, h1;
#pragma unroll
  for (int i = 0; i < 8; ++i) { h0[i] = o[i]; h1[i] = o[8 + i]; }
  *(us8v*)(base) = h0;          // half 0 (ch 0-7)
  *(us8v*)(base + 256) = h1;    // half 1 (ch 8-15)
}

// fold one MFMA result into a running min with a depth-3 min3 tree (8 min3)
#define FOLD(mreg, a)                                              \
  {                                                                \
    const float u0 = fminf(fminf(a[0], a[1]), a[2]);               \
    const float u1 = fminf(fminf(a[3], a[4]), a[5]);               \
    const float u2 = fminf(fminf(a[6], a[7]), a[8]);               \
    const float u3 = fminf(fminf(a[9], a[10]), a[11]);             \
    const float u4 = fminf(fminf(a[12], a[13]), a[14]);            \
    const float v0 = fminf(fminf(u0, u1), u2);                     \
    const float v1 = fminf(fminf(u3, u4), a[15]);                  \
    mreg = fminf(fminf(mreg, v0), v1);                             \
  }

// ---------------------------------------------------------------------------
// Main: 256 blocks = dir(2) x ag(16) x cc(8), 512 thr (8 waves), 64 KB LDS
// (2 x 32 KB dbuf), 1 block/CU in practice.  Each wave owns 4 A-tiles
// (NAMED g0..g3 — r11 lesson: g[4] arrays + launch_bounds(512,4)'s 128-VGPR
// cap made the compiler spill MFMA results to scratch: VGPR=64, 1.5 MB
// fetch + 3 MB write PER BLOCK, 690 us.  launch_bounds(512,2) = 256-VGPR
// budget).  B-chunk 2048 pts in 2 staged rounds; inner: 1 ds_read_b128 ->
// 4 MFMA -> 32 min3 (one f32x16 live at a time).  atomicMin combine.
// ---------------------------------------------------------------------------
__global__ __launch_bounds__(512, 2) void chamfer_mfma_kernel(
    const float* __restrict__ adv, const float* __restrict__ ori,
    const unsigned short* __restrict__ Fall,
    unsigned int* __restrict__ minbuf) {
  __shared__ short lds[2][16384];  // 2 x 32 KB

  const int bid = blockIdx.x;
  const int dir = bid >> 7;
  const int rr  = bid & 127;
  const int ag  = rr >> 3;   // 0..15 A-group (1024 pts)
  const int cc  = rr & 7;    // 0..7  B-chunk (2048 pts = 64 tiles)

  const float* __restrict__ A = dir ? ori : adv;
  const unsigned short* __restrict__ F = Fall + (size_t)(1 - dir) * (NPTS * 16);

  const int tid  = threadIdx.x;
  const int w    = tid >> 6;
  const int lane = tid & 63;
  const int col  = lane & 31;
  const int half = lane >> 5;

  const unsigned short* Fc = F + (size_t)cc * (2048 * 16);  // chunk base

  auto stage = [&](int r, int buf) {
    const char* src = (const char*)(Fc + r * 16384);
#pragma unroll
    for (int s = 0; s < 4; ++s) {
      const int seg = w * 4 + s;
      __builtin_amdgcn_global_load_lds(
          (const __attribute__((address_space(1))) void*)(src + seg * 1024 + lane * 16),
          (__attribute__((address_space(3))) void*)((char*)&lds[buf][0] + seg * 1024),
          16, 0, 0);
    }
  };

  stage(0, 0);  // issue round-0 staging before G-frag build (overlaps)

  // ---- G fragments for this wave's 4 A-tiles (named; no arrays) ----
  const unsigned short ONE = 0x3F80;
  const int qbase = ag * 1024 + w * 128 + col;
  const int q0 = qbase, q1 = qbase + 32, q2i = qbase + 64, q3 = qbase + 96;

  bf16x8 g0, g1, g2, g3;
  float p20, p21, p22, p23;
#define MKG(greg, p2reg, qi)                                            \
  {                                                                     \
    const float x = A[(qi) * 3], y = A[(qi) * 3 + 1], z = A[(qi) * 3 + 2]; \
    p2reg = x * x + y * y + z * z;                                      \
    const unsigned short xh = f2bf(x), xl = f2bf(x - bf2f(xh));         \
    const unsigned short yh = f2bf(y), yl = f2bf(y - bf2f(yh));         \
    const unsigned short zh = f2bf(z), zl = f2bf(z - bf2f(zh));         \
    greg[0] = half ? zh : xh; greg[1] = half ? zl : xl;                 \
    greg[2] = half ? zh : xh; greg[3] = half ? zl : xl;                 \
    greg[4] = half ? ONE : yh; greg[5] = half ? ONE : yl;               \
    greg[6] = half ? ONE : yh; greg[7] = half ? (unsigned short)0 : yl; \
  }
  MKG(g0, p20, q0)
  MKG(g1, p21, q1)
  MKG(g2, p22, q2i)
  MKG(g3, p23, q3)
#undef MKG

  const f32x16 zacc = {};
  float m0 = 1e30f, m1 = 1e30f, m2 = 1e30f, m3 = 1e30f;

#pragma unroll
  for (int r = 0; r < 2; ++r) {
    __syncthreads();  // vmcnt(0) drain before barrier -> buf ready
    if (r == 0) stage(1, 1);
    const char* Lb = (const char*)&lds[r][0] + lane * 16;  // col*16 + half*512

#pragma unroll
    for (int t = 0; t < 32; ++t) {
      const bf16x8 f = *(const bf16x8*)(Lb + t * 1024);  // imm-offset ds_read_b128
      {
        const f32x16 a = __builtin_amdgcn_mfma_f32_32x32x16_bf16(f, g0, zacc, 0, 0, 0);
        FOLD(m0, a)
      }
      {
        const f32x16 a = __builtin_amdgcn_mfma_f32_32x32x16_bf16(f, g1, zacc, 0, 0, 0);
        FOLD(m1, a)
      }
      {
        const f32x16 a = __builtin_amdgcn_mfma_f32_32x32x16_bf16(f, g2, zacc, 0, 0, 0);
        FOLD(m2, a)
      }
      {
        const f32x16 a = __builtin_amdgcn_mfma_f32_32x32x16_bf16(f, g3, zacc, 0, 0, 0);
        FOLD(m3, a)
      }
    }
  }

  // ---- epilogue: fold halves (rows in lanes^32), add |q|^2, atomicMin ----
#define EPI(mreg, p2reg, qi)                                       \
  {                                                                \
    const float mc = fminf(mreg, __shfl_xor(mreg, 32));            \
    const float d = fmaxf(mc + p2reg, 0.0f);                       \
    if (half == 0)                                                 \
      atomicMin(&minbuf[dir * NPTS + (qi)], __float_as_uint(d));   \
  }
  EPI(m0, p20, q0)
  EPI(m1, p21, q1)
  EPI(m2, p22, q2i)
  EPI(m3, p23, q3)
#undef EPI
}

// Single block: sum all 2*NPTS per-point mins (uint4-vectorized), /NPTS.
__global__ __launch_bounds__(1024) void chamfer_reduce_kernel(
    const unsigned int* __restrict__ minbuf, float* __restrict__ out) {
  __shared__ float red[1024];
  const int tid = threadIdx.x;
  const uint4* mb4 = (const uint4*)minbuf;
  float s = 0.0f;
#pragma unroll
  for (int it = 0; it < 8; ++it) {
    const uint4 v = mb4[it * 1024 + tid];
    s += __uint_as_float(v.x) + __uint_as_float(v.y) +
         __uint_as_float(v.z) + __uint_as_float(v.w);
  }
  red[tid] = s;
  __syncthreads();
  for (int off = 512; off > 0; off >>= 1) {
    if (tid < off) red[tid] += red[tid + off];
    __syncthreads();
  }
  if (tid == 0) out[0] = red[0] * (1.0f / (float)NPTS);  // LOSS_WEIGHT = 1
}

// ---------------------------------------------------------------------------
// Fallback (ws too small): round-2 VALU kernel + memset + reduce.
// ---------------------------------------------------------------------------
__global__ __launch_bounds__(256) void chamfer_valu_kernel(
    const float* __restrict__ adv, const float* __restrict__ ori,
    unsigned int* __restrict__ minbuf) {
  __shared__ float4 bt[512];
  const int bx = blockIdx.x;
  const int c = bx & 31;
  const int t = bx >> 5;
  const int dir = t & 1;
  const int ab = t >> 1;
  const float* __restrict__ A = dir ? ori : adv;
  const float* __restrict__ B = dir ? adv : ori;
  const int tid = threadIdx.x;
  for (int j = tid; j < 512; j += 256) {
    const float* bp = B + (size_t)(c * 512 + j) * 3;
    const float x = bp[0], y = bp[1], z = bp[2];
    bt[j] = make_float4(x, y, z, 0.5f * (x * x + y * y + z * z));
  }
  float nax[8], nay[8], naz[8], a2[8], mn[8];
#pragma unroll
  for (int k = 0; k < 8; ++k) {
    const int idx = ab * 2048 + k * 256 + tid;
    const float* ap = A + (size_t)idx * 3;
    const float x = ap[0], y = ap[1], z = ap[2];
    nax[k] = -x; nay[k] = -y; naz[k] = -z;
    a2[k] = x * x + y * y + z * z;
    mn[k] = 1e30f;
  }
  __syncthreads();
#pragma unroll 4
  for (int j = 0; j < 512; j += 2) {
    const float4 b0 = bt[j];
    const float4 b1 = bt[j + 1];
#pragma unroll
    for (int k = 0; k < 8; ++k) {
      const float t0 = fmaf(nax[k], b0.x, fmaf(nay[k], b0.y, fmaf(naz[k], b0.z, b0.w)));
      const float t1 = fmaf(nax[k], b1.x, fmaf(nay[k], b1.y, fmaf(naz[k], b1.z, b1.w)));
      mn[k] = fminf(fminf(mn[k], t0), t1);
    }
  }
#pragma unroll
  for (int k = 0; k < 8; ++k) {
    const int idx = ab * 2048 + k * 256 + tid;
    const float v = fmaf(2.0f, mn[k], a2[k]);
    atomicMin(&minbuf[dir * NPTS + idx], __float_as_uint(v));
  }
}

extern "C" void kernel_launch(void* const* d_in, const int* in_sizes, int n_in,
                              void* d_out, int out_size, void* d_ws, size_t ws_size,
                              hipStream_t stream) {
  const float* adv = (const float*)d_in[0];
  const float* ori = (const float*)d_in[1];
  float* out = (float*)d_out;
  unsigned int* minbuf = (unsigned int*)d_ws;

  const size_t need = 131072 + (size_t)2 * NPTS * 16 * sizeof(unsigned short);  // 128K + 1M

  if (ws_size >= need) {
    unsigned short* Fall = (unsigned short*)((char*)d_ws + 131072);
    prepack_kernel<<<128, 256, 0, stream>>>(adv, ori, Fall, minbuf);  // also inits minbuf
    chamfer_mfma_kernel<<<256, 512, 0, stream>>>(adv, ori, Fall, minbuf);
  } else {
    (void)hipMemsetAsync(minbuf, 0x7F, (size_t)(2 * NPTS) * sizeof(unsigned int), stream);
    chamfer_valu_kernel<<<1024, 256, 0, stream>>>(adv, ori, minbuf);
  }
  chamfer_reduce_kernel<<<1, 1024, 0, stream>>>(minbuf, out);
}